// Round 4
// baseline (215.401 us; speedup 1.0000x reference)
//
#include <hip/hip_runtime.h>
#include <cstdint>

#define EPS 1e-5f

typedef unsigned long long u64;
typedef unsigned int u32;

__device__ __forceinline__ int clampi(int v, int lo, int hi) {
    return v < lo ? lo : (v > hi ? hi : v);
}

// ---------------- prep_small: all tiny packing + bn-constant folding ----------------

__global__ void prep_small(
    const float* __restrict__ conv1_w, const float* __restrict__ conv2_w,
    const float* __restrict__ fc2_w,
    const float* __restrict__ g1, const float* __restrict__ b1,
    const float* __restrict__ m1, const float* __restrict__ v1,
    const float* __restrict__ g2, const float* __restrict__ b2,
    const float* __restrict__ m2, const float* __restrict__ v2,
    float* __restrict__ s1, u64* __restrict__ w2p, u64* __restrict__ w2pk,
    float4* __restrict__ bnc1, float4* __restrict__ bnc2)
{
    int t = blockIdx.x * 256 + threadIdx.x;
    if (t < 576) {
        s1[t] = (conv1_w[t] >= 0.f) ? 1.f : -1.f;
    } else if (t < 1152) {
        int u = t - 576;
        int co = u / 9, tap = u % 9;
        u64 word = 0;
        for (int ci = 0; ci < 64; ci++)
            word |= (u64)(conv2_w[(co * 64 + ci) * 9 + tap] >= 0.f) << ci;
        w2p[u] = word;
    } else if (t < 1472) {
        int u = t - 1152;
        int o = u / 32, k = u % 32;
        u64 word = 0;
        for (int j = 0; j < 64; j++)
            word |= (u64)(fc2_w[o * 2048 + k * 64 + j] >= 0.f) << j;
        w2pk[u] = word;
    } else if (t < 1536) {
        int ch = t - 1472;
        bnc1[ch] = make_float4(m1[ch], g1[ch] / sqrtf(v1[ch] + EPS), b1[ch], 0.f);
    } else if (t < 1600) {
        int ch = t - 1536;
        bnc2[ch] = make_float4(m2[ch], g2[ch] / sqrtf(v2[ch] + EPS), b2[ch], 0.f);
    }
}

// ---------------- prep_fc1: LDS-staged coalesced repack ----------------
// fc1_w [2048,3136] (flat idx = c*49+p) -> wp[p*2048+o], bit c

__global__ __launch_bounds__(256) void prep_fc1(const float* __restrict__ w,
                                                u64* __restrict__ wp) {
    __shared__ float ls[3136];
    int o = blockIdx.x;
    const float4* row4 = (const float4*)(w + o * 3136);
    for (int i = threadIdx.x; i < 784; i += 256)
        ((float4*)ls)[i] = row4[i];
    __syncthreads();
    int p = threadIdx.x;
    if (p < 49) {
        u64 word = 0;
        #pragma unroll
        for (int c = 0; c < 64; c++)
            word |= (u64)(ls[c * 49 + p] >= 0.f) << c;
        wp[p * 2048 + o] = word;
    }
}

// ---------- K1: conv1 + bn1 + sign + maxpool -> packed [B,14,14] ----------
// grid (1568, 2): 32 channels/thread; weights + bn constants wave-uniform
// -> scalar loads. bn affine monotone in v -> min/max epilogue (exact).

__global__ __launch_bounds__(256) void k_conv1(
    const float* __restrict__ x, const float* __restrict__ s1,
    const float4* __restrict__ bnc1, u64* __restrict__ out1)
{
    int tid = threadIdx.x;
    int g = blockIdx.y;
    int base = g * 32;

    int idx = blockIdx.x * 256 + tid;          // b*196 + p, exactly 401408
    int b = idx / 196, p = idx % 196;
    int pi = p / 14, pj = p % 14;

    const float* xb = x + b * 784;
    int rr[4], cc[4];
    #pragma unroll
    for (int r = 0; r < 4; r++) rr[r] = clampi(2 * pi - 1 + r, 0, 27) * 28;
    #pragma unroll
    for (int c = 0; c < 4; c++) cc[c] = clampi(2 * pj - 1 + c, 0, 27);
    float patch[4][4];
    #pragma unroll
    for (int r = 0; r < 4; r++)
        #pragma unroll
        for (int c = 0; c < 4; c++)
            patch[r][c] = xb[rr[r] + cc[c]];

    u32 word = 0;
    #pragma unroll 4
    for (int ch = 0; ch < 32; ch++) {
        const float* w = s1 + (base + ch) * 9;  // uniform -> s_load
        float v00 = 0.f, v01 = 0.f, v10 = 0.f, v11 = 0.f;
        #pragma unroll
        for (int ki = 0; ki < 3; ki++)
            #pragma unroll
            for (int kj = 0; kj < 3; kj++) {
                float ww = w[ki * 3 + kj];
                v00 += patch[ki][kj] * ww;
                v01 += patch[ki][kj + 1] * ww;
                v10 += patch[ki + 1][kj] * ww;
                v11 += patch[ki + 1][kj + 1] * ww;
            }
        float vmin = fminf(fminf(v00, v01), fminf(v10, v11));
        float vmax = fmaxf(fmaxf(v00, v01), fmaxf(v10, v11));
        float4 c4 = bnc1[base + ch];            // uniform -> s_load_dwordx4
        int bit = (((vmin - c4.x) * c4.y + c4.z) >= 0.f) |
                  (((vmax - c4.x) * c4.y + c4.z) >= 0.f);
        word |= (u32)bit << ch;
    }
    ((u32*)out1)[idx * 2 + g] = word;           // little-endian u64 halves
}

// ---------- K2: conv2 + bn2 + sign + maxpool -> packed [B,7,7] ----------
// grid (392, 2): 32 output channels/thread; weights scalar-loaded.

__global__ __launch_bounds__(256) void k_conv2(
    const u64* __restrict__ in, const u64* __restrict__ w2p,
    const float4* __restrict__ bnc2, u64* __restrict__ out2)
{
    int tid = threadIdx.x;
    int g = blockIdx.y;
    int base = g * 32;

    int idx = blockIdx.x * 256 + tid;          // b*49 + p, exactly 100352
    int b = idx / 49, p = idx % 49;
    int pi = p / 7, pj = p % 7;

    const u64* ib = in + b * 196;
    int rr[4], cc[4];
    #pragma unroll
    for (int r = 0; r < 4; r++) rr[r] = clampi(2 * pi - 1 + r, 0, 13) * 14;
    #pragma unroll
    for (int c = 0; c < 4; c++) cc[c] = clampi(2 * pj - 1 + c, 0, 13);
    u64 a[4][4];
    #pragma unroll
    for (int r = 0; r < 4; r++)
        #pragma unroll
        for (int c = 0; c < 4; c++)
            a[r][c] = ib[rr[r] + cc[c]];

    u32 word = 0;
    #pragma unroll 2
    for (int co = 0; co < 32; co++) {
        const u64* w = w2p + (base + co) * 9;   // uniform -> s_load
        int s00 = 0, s01 = 0, s10 = 0, s11 = 0;
        #pragma unroll
        for (int ki = 0; ki < 3; ki++)
            #pragma unroll
            for (int kj = 0; kj < 3; kj++) {
                u64 ww = w[ki * 3 + kj];
                s00 += __popcll(a[ki][kj] ^ ww);
                s01 += __popcll(a[ki][kj + 1] ^ ww);
                s10 += __popcll(a[ki + 1][kj] ^ ww);
                s11 += __popcll(a[ki + 1][kj + 1] ^ ww);
            }
        int smin = min(min(s00, s01), min(s10, s11));
        int smax = max(max(s00, s01), max(s10, s11));
        float4 c4 = bnc2[base + co];
        int bit = (((float)(576 - 2 * smin) - c4.x) * c4.y + c4.z >= 0.f) |
                  (((float)(576 - 2 * smax) - c4.x) * c4.y + c4.z >= 0.f);
        word |= (u32)bit << co;
    }
    ((u32*)out2)[idx * 2 + g] = word;
}

// ---------- K3: fc1 + bn3 + sign -> packed [B,32] ----------
// Activations are wave-uniform -> scalar loads (no LDS, no syncthreads).
// Weights wp[p*2048+o] coalesced vector loads across o=tid.

#define NB 16

__global__ __launch_bounds__(256) void k_fc1(
    const u64* __restrict__ act, const u64* __restrict__ wp,
    const float* __restrict__ g, const float* __restrict__ bt,
    const float* __restrict__ mn, const float* __restrict__ vr,
    u64* __restrict__ out3)
{
    int tid = threadIdx.x;
    int btile = blockIdx.x >> 3;               // 128 tiles of NB batches
    int otile = blockIdx.x & 7;                // 8 tiles of 256 outputs
    int b0 = btile * NB;
    int o = otile * 256 + tid;
    const u64* ab = act + b0 * 49;

    int sums[NB];
    #pragma unroll
    for (int i = 0; i < NB; i++) sums[i] = 0;

    for (int p = 0; p < 49; p++) {
        u64 w = wp[p * 2048 + o];
        #pragma unroll
        for (int bb = 0; bb < NB; bb++)
            sums[bb] += __popcll(ab[bb * 49 + p] ^ w);   // ab idx uniform -> s_load
    }

    float iv = g[o] / sqrtf(vr[o] + EPS);
    float m = mn[o], be = bt[o];
    #pragma unroll
    for (int bb = 0; bb < NB; bb++) {
        float y = ((float)(3136 - 2 * sums[bb]) - m) * iv + be;
        u64 ball = __ballot(y >= 0.f);
        if ((tid & 63) == 0) out3[(b0 + bb) * 32 + (o >> 6)] = ball;
    }
}

// ---------- K4: fc2 + scale ----------

__global__ void k_fc2(const u64* __restrict__ act, const u64* __restrict__ w2,
                      const float* __restrict__ scale, float* __restrict__ out)
{
    int idx = blockIdx.x * 256 + threadIdx.x;  // b*16 + o (o<10 active)
    if (idx >= 2048 * 16) return;
    int b = idx >> 4, o = idx & 15;
    if (o >= 10) return;
    int s = 0;
    #pragma unroll
    for (int k = 0; k < 32; k++)
        s += __popcll(act[b * 32 + k] ^ w2[o * 32 + k]);
    out[b * 10 + o] = scale[0] * (float)(2048 - 2 * s);
}

// ---------------- launch ----------------

extern "C" void kernel_launch(void* const* d_in, const int* in_sizes, int n_in,
                              void* d_out, int out_size, void* d_ws, size_t ws_size,
                              hipStream_t stream) {
    const float* x        = (const float*)d_in[0];
    const float* conv1_w  = (const float*)d_in[1];
    const float* bn1_g    = (const float*)d_in[2];
    const float* bn1_b    = (const float*)d_in[3];
    const float* bn1_m    = (const float*)d_in[4];
    const float* bn1_v    = (const float*)d_in[5];
    const float* conv2_w  = (const float*)d_in[6];
    const float* bn2_g    = (const float*)d_in[7];
    const float* bn2_b    = (const float*)d_in[8];
    const float* bn2_m    = (const float*)d_in[9];
    const float* bn2_v    = (const float*)d_in[10];
    const float* fc1_w    = (const float*)d_in[11];
    const float* bn3_g    = (const float*)d_in[12];
    const float* bn3_b    = (const float*)d_in[13];
    const float* bn3_m    = (const float*)d_in[14];
    const float* bn3_v    = (const float*)d_in[15];
    const float* fc2_w    = (const float*)d_in[16];
    const float* scale    = (const float*)d_in[17];
    float* out = (float*)d_out;

    char* ws = (char*)d_ws;
    float*  s1   = (float*) (ws + 0);          //   2304 B
    u64*    w2p  = (u64*)   (ws + 2560);       //   4608 B (ends 7168)
    float4* bnc1 = (float4*)(ws + 7168);       //   1024 B (ends 8192)
    u64*    wp   = (u64*)   (ws + 8192);       // 802816 B (ends 811008)
    u64*    w2pk = (u64*)   (ws + 811008);     //   2560 B (ends 813568)
    float4* bnc2 = (float4*)(ws + 813568);     //   1024 B (ends 814592)
    u64*    out1 = (u64*)   (ws + 819200);     // 3211264 B (ends 4030464)
    u64*    out2 = (u64*)   (ws + 4030464);    // 802816 B (ends 4833280)
    u64*    out3 = (u64*)   (ws + 4833280);    // 524288 B (ends 5357568)

    hipLaunchKernelGGL(prep_small, dim3(7), dim3(256), 0, stream,
                       conv1_w, conv2_w, fc2_w,
                       bn1_g, bn1_b, bn1_m, bn1_v,
                       bn2_g, bn2_b, bn2_m, bn2_v,
                       s1, w2p, w2pk, bnc1, bnc2);
    hipLaunchKernelGGL(prep_fc1, dim3(2048), dim3(256), 0, stream, fc1_w, wp);

    hipLaunchKernelGGL(k_conv1, dim3(1568, 2), dim3(256), 0, stream,
                       x, s1, bnc1, out1);
    hipLaunchKernelGGL(k_conv2, dim3(392, 2), dim3(256), 0, stream,
                       out1, w2p, bnc2, out2);
    hipLaunchKernelGGL(k_fc1, dim3(1024), dim3(256), 0, stream,
                       out2, wp, bn3_g, bn3_b, bn3_m, bn3_v, out3);
    hipLaunchKernelGGL(k_fc2, dim3(128), dim3(256), 0, stream,
                       out3, w2pk, scale, out);
}

// Round 5
// 209.168 us; speedup vs baseline: 1.0298x; 1.0298x over previous
//
#include <hip/hip_runtime.h>
#include <cstdint>

#define EPS 1e-5f

typedef unsigned long long u64;
typedef unsigned int u32;
typedef unsigned short u16;
typedef unsigned char u8;

__device__ __forceinline__ int clampi(int v, int lo, int hi) {
    return v < lo ? lo : (v > hi ? hi : v);
}

// ---------------- prep_small: all tiny packing + bn-constant folding ----------------

__global__ void prep_small(
    const float* __restrict__ conv1_w, const float* __restrict__ conv2_w,
    const float* __restrict__ fc2_w,
    const float* __restrict__ g1, const float* __restrict__ b1,
    const float* __restrict__ m1, const float* __restrict__ v1,
    const float* __restrict__ g2, const float* __restrict__ b2,
    const float* __restrict__ m2, const float* __restrict__ v2,
    float* __restrict__ s1, u64* __restrict__ w2p, u64* __restrict__ w2pk,
    float4* __restrict__ bnc1, float4* __restrict__ bnc2)
{
    int t = blockIdx.x * 256 + threadIdx.x;
    if (t < 576) {
        s1[t] = (conv1_w[t] >= 0.f) ? 1.f : -1.f;
    } else if (t < 1152) {
        int u = t - 576;
        int co = u / 9, tap = u % 9;
        u64 word = 0;
        for (int ci = 0; ci < 64; ci++)
            word |= (u64)(conv2_w[(co * 64 + ci) * 9 + tap] >= 0.f) << ci;
        w2p[u] = word;
    } else if (t < 1472) {
        int u = t - 1152;
        int o = u / 32, k = u % 32;
        u64 word = 0;
        for (int j = 0; j < 64; j++)
            word |= (u64)(fc2_w[o * 2048 + k * 64 + j] >= 0.f) << j;
        w2pk[u] = word;
    } else if (t < 1536) {
        int ch = t - 1472;
        bnc1[ch] = make_float4(m1[ch], g1[ch] / sqrtf(v1[ch] + EPS), b1[ch], 0.f);
    } else if (t < 1600) {
        int ch = t - 1536;
        bnc2[ch] = make_float4(m2[ch], g2[ch] / sqrtf(v2[ch] + EPS), b2[ch], 0.f);
    }
}

// ---------------- prep_fc1: LDS-staged coalesced repack ----------------
// fc1_w [2048,3136] (flat idx = c*49+p) -> wp[p*2048+o], bit c

__global__ __launch_bounds__(256) void prep_fc1(const float* __restrict__ w,
                                                u64* __restrict__ wp) {
    __shared__ float ls[3136];
    int o = blockIdx.x;
    const float4* row4 = (const float4*)(w + o * 3136);
    for (int i = threadIdx.x; i < 784; i += 256)
        ((float4*)ls)[i] = row4[i];
    __syncthreads();
    int p = threadIdx.x;
    if (p < 49) {
        u64 word = 0;
        #pragma unroll
        for (int c = 0; c < 64; c++)
            word |= (u64)(ls[c * 49 + p] >= 0.f) << c;
        wp[p * 2048 + o] = word;
    }
}

// ---------- K1: conv1 + bn1 + sign + maxpool -> packed [B,14,14] ----------
// grid (1568, 4): 16 channels/thread, 25088 waves (~24/SIMD).
// Weights + bn constants wave-uniform -> scalar loads.
// bn affine monotone in v -> min/max epilogue (bit-exact).

__global__ __launch_bounds__(256) void k_conv1(
    const float* __restrict__ x, const float* __restrict__ s1,
    const float4* __restrict__ bnc1, u64* __restrict__ out1)
{
    int tid = threadIdx.x;
    int g = blockIdx.y;
    int base = g * 16;

    int idx = blockIdx.x * 256 + tid;          // b*196 + p, exactly 401408
    int b = idx / 196, p = idx % 196;
    int pi = p / 14, pj = p % 14;

    const float* xb = x + b * 784;
    int rr[4], cc[4];
    #pragma unroll
    for (int r = 0; r < 4; r++) rr[r] = clampi(2 * pi - 1 + r, 0, 27) * 28;
    #pragma unroll
    for (int c = 0; c < 4; c++) cc[c] = clampi(2 * pj - 1 + c, 0, 27);
    float patch[4][4];
    #pragma unroll
    for (int r = 0; r < 4; r++)
        #pragma unroll
        for (int c = 0; c < 4; c++)
            patch[r][c] = xb[rr[r] + cc[c]];

    u32 word = 0;
    #pragma unroll 4
    for (int ch = 0; ch < 16; ch++) {
        const float* w = s1 + (base + ch) * 9;  // uniform -> s_load
        float v00 = 0.f, v01 = 0.f, v10 = 0.f, v11 = 0.f;
        #pragma unroll
        for (int ki = 0; ki < 3; ki++)
            #pragma unroll
            for (int kj = 0; kj < 3; kj++) {
                float ww = w[ki * 3 + kj];
                v00 += patch[ki][kj] * ww;
                v01 += patch[ki][kj + 1] * ww;
                v10 += patch[ki + 1][kj] * ww;
                v11 += patch[ki + 1][kj + 1] * ww;
            }
        float vmin = fminf(fminf(v00, v01), fminf(v10, v11));
        float vmax = fmaxf(fmaxf(v00, v01), fmaxf(v10, v11));
        float4 c4 = bnc1[base + ch];            // uniform -> s_load_dwordx4
        int bit = (((vmin - c4.x) * c4.y + c4.z) >= 0.f) |
                  (((vmax - c4.x) * c4.y + c4.z) >= 0.f);
        word |= (u32)bit << ch;
    }
    ((u16*)out1)[idx * 4 + g] = (u16)word;      // little-endian u64 quarters
}

// ---------- K2: conv2 + bn2 + sign + maxpool -> packed [B,7,7] ----------
// grid (392, 8): 8 output channels/thread, 12544 waves (~12/SIMD).
// Weights scalar-loaded (18 dwords/thread, hoistable); byte store
// assembles little-endian u64.

__global__ __launch_bounds__(256) void k_conv2(
    const u64* __restrict__ in, const u64* __restrict__ w2p,
    const float4* __restrict__ bnc2, u64* __restrict__ out2)
{
    int tid = threadIdx.x;
    int g = blockIdx.y;
    int base = g * 8;

    int idx = blockIdx.x * 256 + tid;          // b*49 + p, exactly 100352
    int b = idx / 49, p = idx % 49;
    int pi = p / 7, pj = p % 7;

    const u64* ib = in + b * 196;
    int rr[4], cc[4];
    #pragma unroll
    for (int r = 0; r < 4; r++) rr[r] = clampi(2 * pi - 1 + r, 0, 13) * 14;
    #pragma unroll
    for (int c = 0; c < 4; c++) cc[c] = clampi(2 * pj - 1 + c, 0, 13);
    u64 a[4][4];
    #pragma unroll
    for (int r = 0; r < 4; r++)
        #pragma unroll
        for (int c = 0; c < 4; c++)
            a[r][c] = ib[rr[r] + cc[c]];

    u32 word = 0;
    #pragma unroll
    for (int co = 0; co < 8; co++) {
        const u64* w = w2p + (base + co) * 9;   // uniform -> s_load
        int s00 = 0, s01 = 0, s10 = 0, s11 = 0;
        #pragma unroll
        for (int ki = 0; ki < 3; ki++)
            #pragma unroll
            for (int kj = 0; kj < 3; kj++) {
                u64 ww = w[ki * 3 + kj];
                s00 += __popcll(a[ki][kj] ^ ww);
                s01 += __popcll(a[ki][kj + 1] ^ ww);
                s10 += __popcll(a[ki + 1][kj] ^ ww);
                s11 += __popcll(a[ki + 1][kj + 1] ^ ww);
            }
        int smin = min(min(s00, s01), min(s10, s11));
        int smax = max(max(s00, s01), max(s10, s11));
        float4 c4 = bnc2[base + co];
        int bit = (((float)(576 - 2 * smin) - c4.x) * c4.y + c4.z >= 0.f) |
                  (((float)(576 - 2 * smax) - c4.x) * c4.y + c4.z >= 0.f);
        word |= (u32)bit << co;
    }
    ((u8*)out2)[idx * 8 + g] = (u8)word;        // little-endian u64 bytes
}

// ---------- K3: fc1 + bn3 + sign -> packed [B,32] ----------
// NB=8: 2048 blocks (~8 waves/SIMD); activations wave-uniform -> scalar loads.

#define NB 8

__global__ __launch_bounds__(256) void k_fc1(
    const u64* __restrict__ act, const u64* __restrict__ wp,
    const float* __restrict__ g, const float* __restrict__ bt,
    const float* __restrict__ mn, const float* __restrict__ vr,
    u64* __restrict__ out3)
{
    int tid = threadIdx.x;
    int btile = blockIdx.x >> 3;               // 256 tiles of NB batches
    int otile = blockIdx.x & 7;                // 8 tiles of 256 outputs
    int b0 = btile * NB;
    int o = otile * 256 + tid;
    const u64* ab = act + b0 * 49;

    int sums[NB];
    #pragma unroll
    for (int i = 0; i < NB; i++) sums[i] = 0;

    for (int p = 0; p < 49; p++) {
        u64 w = wp[p * 2048 + o];
        #pragma unroll
        for (int bb = 0; bb < NB; bb++)
            sums[bb] += __popcll(ab[bb * 49 + p] ^ w);   // ab idx uniform -> s_load
    }

    float iv = g[o] / sqrtf(vr[o] + EPS);
    float m = mn[o], be = bt[o];
    #pragma unroll
    for (int bb = 0; bb < NB; bb++) {
        float y = ((float)(3136 - 2 * sums[bb]) - m) * iv + be;
        u64 ball = __ballot(y >= 0.f);
        if ((tid & 63) == 0) out3[(b0 + bb) * 32 + (o >> 6)] = ball;
    }
}

// ---------- K4: fc2 + scale ----------

__global__ void k_fc2(const u64* __restrict__ act, const u64* __restrict__ w2,
                      const float* __restrict__ scale, float* __restrict__ out)
{
    int idx = blockIdx.x * 256 + threadIdx.x;  // b*16 + o (o<10 active)
    if (idx >= 2048 * 16) return;
    int b = idx >> 4, o = idx & 15;
    if (o >= 10) return;
    int s = 0;
    #pragma unroll
    for (int k = 0; k < 32; k++)
        s += __popcll(act[b * 32 + k] ^ w2[o * 32 + k]);
    out[b * 10 + o] = scale[0] * (float)(2048 - 2 * s);
}

// ---------------- launch ----------------

extern "C" void kernel_launch(void* const* d_in, const int* in_sizes, int n_in,
                              void* d_out, int out_size, void* d_ws, size_t ws_size,
                              hipStream_t stream) {
    const float* x        = (const float*)d_in[0];
    const float* conv1_w  = (const float*)d_in[1];
    const float* bn1_g    = (const float*)d_in[2];
    const float* bn1_b    = (const float*)d_in[3];
    const float* bn1_m    = (const float*)d_in[4];
    const float* bn1_v    = (const float*)d_in[5];
    const float* conv2_w  = (const float*)d_in[6];
    const float* bn2_g    = (const float*)d_in[7];
    const float* bn2_b    = (const float*)d_in[8];
    const float* bn2_m    = (const float*)d_in[9];
    const float* bn2_v    = (const float*)d_in[10];
    const float* fc1_w    = (const float*)d_in[11];
    const float* bn3_g    = (const float*)d_in[12];
    const float* bn3_b    = (const float*)d_in[13];
    const float* bn3_m    = (const float*)d_in[14];
    const float* bn3_v    = (const float*)d_in[15];
    const float* fc2_w    = (const float*)d_in[16];
    const float* scale    = (const float*)d_in[17];
    float* out = (float*)d_out;

    char* ws = (char*)d_ws;
    float*  s1   = (float*) (ws + 0);          //   2304 B
    u64*    w2p  = (u64*)   (ws + 2560);       //   4608 B (ends 7168)
    float4* bnc1 = (float4*)(ws + 7168);       //   1024 B (ends 8192)
    u64*    wp   = (u64*)   (ws + 8192);       // 802816 B (ends 811008)
    u64*    w2pk = (u64*)   (ws + 811008);     //   2560 B (ends 813568)
    float4* bnc2 = (float4*)(ws + 813568);     //   1024 B (ends 814592)
    u64*    out1 = (u64*)   (ws + 819200);     // 3211264 B (ends 4030464)
    u64*    out2 = (u64*)   (ws + 4030464);    // 802816 B (ends 4833280)
    u64*    out3 = (u64*)   (ws + 4833280);    // 524288 B (ends 5357568)

    hipLaunchKernelGGL(prep_small, dim3(7), dim3(256), 0, stream,
                       conv1_w, conv2_w, fc2_w,
                       bn1_g, bn1_b, bn1_m, bn1_v,
                       bn2_g, bn2_b, bn2_m, bn2_v,
                       s1, w2p, w2pk, bnc1, bnc2);
    hipLaunchKernelGGL(prep_fc1, dim3(2048), dim3(256), 0, stream, fc1_w, wp);

    hipLaunchKernelGGL(k_conv1, dim3(1568, 4), dim3(256), 0, stream,
                       x, s1, bnc1, out1);
    hipLaunchKernelGGL(k_conv2, dim3(392, 8), dim3(256), 0, stream,
                       out1, w2p, bnc2, out2);
    hipLaunchKernelGGL(k_fc1, dim3(2048), dim3(256), 0, stream,
                       out2, wp, bn3_g, bn3_b, bn3_m, bn3_v, out3);
    hipLaunchKernelGGL(k_fc2, dim3(128), dim3(256), 0, stream,
                       out3, w2pk, scale, out);
}